// Round 9
// baseline (2198.079 us; speedup 1.0000x reference)
//
#include <hip/hip_runtime.h>
#include <math.h>
#include <stdint.h>

// Problem constants
static constexpr int B_ = 128;
static constexpr int T_ = 64;
static constexpr int E_ = 2048;
static constexpr int H_ = 1024;
static constexpr int R_ = 8;
static constexpr int H3_ = 3 * H_;  // 3072

typedef unsigned short u16;
typedef __attribute__((ext_vector_type(8))) __bf16 bf16x8;
typedef __attribute__((ext_vector_type(4))) float f32x4;

__device__ __forceinline__ u16 f2bf(float f) {
    uint32_t x = __float_as_uint(f);
    x += 0x7fffu + ((x >> 16) & 1u);      // round-to-nearest-even
    return (u16)(x >> 16);
}
__device__ __forceinline__ float bf2f(u16 u) {
    return __uint_as_float(((uint32_t)u) << 16);
}

// async global->LDS, 16B per lane; LDS dest = wave-uniform base + lane*16
__device__ __forceinline__ void async_cp16(const u16* g, u16* l) {
    auto* g1 = (const __attribute__((address_space(1))) u16*)g;
    auto* l3 = (__attribute__((address_space(3))) u16*)(uintptr_t)l;
    __builtin_amdgcn_global_load_lds((const __attribute__((address_space(1))) void*)g1,
                                     (__attribute__((address_space(3))) void*)l3,
                                     16, 0, 0);
}

// ---------------------------------------------------------------------------
// LDS tiles use 128-byte rows (BK=64 bf16) with XOR swizzle:
//   phys_byte = (row*128 + col) ^ ((row & 7) << 4)
// global_load_lds writes linearly, so STAGE pre-applies the inverse (same)
// XOR on the global SOURCE column; fragment reads XOR the same mask.
// Measured R3: SQ_LDS_BANK_CONFLICT == 0 with this scheme.
// ---------------------------------------------------------------------------

__global__ __launch_bounds__(256) void zero_kernel(float* __restrict__ p, int n) {
    int i = blockIdx.x * 256 + threadIdx.x;
    if (i < n) p[i] = 0.0f;
}

// fp32 -> bf16 pack: dst[r*cols+c] = bf16(src[r*src_ld + col0 + c])
__global__ __launch_bounds__(256) void conv_bf(
    const float* __restrict__ src, int src_ld, int col0, int cols,
    u16* __restrict__ dst, int total4)
{
    int i4 = blockIdx.x * 256 + threadIdx.x;
    if (i4 >= total4) return;
    int i = i4 * 4;
    int r = i / cols, c = i - r * cols;
    const float4 v = *(const float4*)(src + (size_t)r * src_ld + col0 + c);
    ushort4 o;
    o.x = f2bf(v.x); o.y = f2bf(v.y); o.z = f2bf(v.z); o.w = f2bf(v.w);
    *(ushort4*)(dst + i) = o;
}

// ---------------------------------------------------------------------------
// Fused Phase 1 MFMA GEMM over all three weight sets (unchanged from R7).
// 128x128 tile, BK=64, swizzled LDS, double-buffered.
// Measured R5/R6: 814 TF = 33% dense peak (2-barrier-loop structural ceiling).
// ---------------------------------------------------------------------------
__global__ __launch_bounds__(256) void mfma_p1f(
    const u16* __restrict__ X, int t0, int tcshift,
    const u16* __restrict__ W1,
    const float* __restrict__ bs, const float* __restrict__ ba,
    const float* __restrict__ bo,
    u16* __restrict__ GI, size_t GI_elems)
{
    __shared__ u16 As[2][128 * 64];
    __shared__ u16 Bs[2][128 * 64];
    const int tid = threadIdx.x;
    const int m0 = blockIdx.x * 128;
    const int which = blockIdx.y / 24;
    const int n0 = (blockIdx.y % 24) * 128;
    const int tcmask = (1 << tcshift) - 1;

    const u16* W = W1 + (size_t)which * H3_ * E_;
    const float* bias = (which == 0) ? bs : (which == 1) ? ba : bo;
    u16* C = GI + (size_t)which * GI_elems;

    const int lane = tid & 63;
    const int wm = ((tid >> 6) & 1) * 64;
    const int wn = (tid >> 7) * 64;
    const int fr = lane & 15;
    const int kq = (lane >> 4) * 8;
    const int ldsbase = (tid & 192) * 8;

    const int srow = tid >> 3;
    const int sce  = (((tid & 7) * 16) ^ ((srow & 7) << 4)) >> 1;

    f32x4 acc[4][4] = {};

    auto stage = [&](int buf, int k0) {
#pragma unroll
        for (int p = 0; p < 4; ++p) {
            int mrow = m0 + p * 32 + srow;
            int ro = ((mrow >> tcshift) * T_ + t0 + (mrow & tcmask)) * E_;
            async_cp16(X + ro + k0 + sce, &As[buf][p * 2048 + ldsbase]);
            int nrow = n0 + p * 32 + srow;
            async_cp16(W + (size_t)nrow * E_ + k0 + sce, &Bs[buf][p * 2048 + ldsbase]);
        }
    };
    auto compute = [&](int buf) {
#pragma unroll
        for (int kk = 0; kk < 2; ++kk) {
            bf16x8 a[4], b[4];
#pragma unroll
            for (int i = 0; i < 4; ++i) {
                int ra = wm + i * 16 + fr;
                int oa = (ra * 128 + kk * 64 + kq * 2) ^ ((ra & 7) << 4);
                a[i] = *(const bf16x8*)((const char*)&As[buf][0] + oa);
                int rb = wn + i * 16 + fr;
                int ob = (rb * 128 + kk * 64 + kq * 2) ^ ((rb & 7) << 4);
                b[i] = *(const bf16x8*)((const char*)&Bs[buf][0] + ob);
            }
#pragma unroll
            for (int mt = 0; mt < 4; ++mt)
#pragma unroll
                for (int nt = 0; nt < 4; ++nt)
                    acc[mt][nt] = __builtin_amdgcn_mfma_f32_16x16x32_bf16(
                        a[mt], b[nt], acc[mt][nt], 0, 0, 0);
        }
    };

    stage(0, 0);
    __syncthreads();
    int cur = 0;
    for (int k0 = 64; k0 < E_; k0 += 64) {
        stage(cur ^ 1, k0);
        compute(cur);
        __syncthreads();
        cur ^= 1;
    }
    compute(cur);

#pragma unroll
    for (int mt = 0; mt < 4; ++mt)
#pragma unroll
        for (int nt = 0; nt < 4; ++nt) {
            int n = n0 + wn + nt * 16 + fr;
            float bv = bias[n];
#pragma unroll
            for (int i = 0; i < 4; ++i) {
                int m = m0 + wm + mt * 16 + (lane >> 4) * 4 + i;
                C[(size_t)m * H3_ + n] = f2bf(acc[mt][nt][i] + bv);
            }
        }
}

// ---------------------------------------------------------------------------
// R9: fully fused per-step kernel (GEMM + GRU gate epilogue). One dispatch
// per step replaces {mfma_step + gate_kernel}; G buffer eliminated.
//
// Grid 256 blocks x 512 thr, 1 block/CU (LDS 129KB). Block = (cb, ty):
//   cb 0..15: 64-wide state-column slice c0 = cb*64.
//   ty 0,1  (S): spk gate, rows b in [ty*64,(ty+1)*64).  2 GEMMs:
//               acc1 = A[b,adr]@Whsi^T (gi-suppl), acc2 = A[b,spk]@Whs^T (gh)
//   ty 2,3  (A): adr gate, symmetric (Whai / Wha).
//   ty 4..15(O): others, 64 of 768 rows, 1 GEMM: acc1 = A[b,oth]@Who^T (gh).
// N-tile = 192 "hat" rows = W rows {c0..c0+64) of each gate r/z/n (3 base
// ranges; no repack). Wave layout 2(M=32) x 4(16-col window); wave's 3
// B-frags at hat rows {g*64 + w*16} put r,z,n of the SAME state col in the
// same thread -> gate computed in-register, writes Anew/Abf directly.
//
// RACE NOTE: blocks write state rows other blocks read => Abf is PING-PONGED
// (read Abf_old, write Abf_new; host swaps), as is fp32 A (Aold/Anew).
//
// XCD map: xcd = cb&7 -> a col-block's 16 ty-blocks share one XCD; per-XCD
// B working set = 2 col-slices x 5 W-matrices = 3.8MB <= 4MB L2, and each
// block's W rows are FIXED across all 64 steps -> B stays L2-resident.
// ---------------------------------------------------------------------------
__global__ __launch_bounds__(512) void step_fused(
    const u16* __restrict__ Abf_old, u16* __restrict__ Abf_new,
    const float* __restrict__ Aold, float* __restrict__ Anew,
    const int* __restrict__ dig, int t, int tloc, int Tc,
    const u16* __restrict__ Whsi, const u16* __restrict__ Whs,
    const u16* __restrict__ Whai, const u16* __restrict__ Wha,
    const u16* __restrict__ Who,
    const u16* __restrict__ GIX, const u16* __restrict__ GIA,
    const u16* __restrict__ GIO,
    const float* __restrict__ ws_bhh, const float* __restrict__ wa_bhh,
    const float* __restrict__ wo_bhh)
{
    __shared__ u16 Bs1[2][192 * 64];   // 24 KB each buf
    __shared__ u16 Bs2[2][192 * 64];
    __shared__ u16 As1[2][64 * 64];    //  8 KB each buf
    __shared__ u16 As2[2][64 * 64];
    __shared__ int roffA1[64], roffA2[64], bIdx[64];

    const int tid = threadIdx.x;
    const int wgid = blockIdx.x;
    const int xcd = wgid & 7;
    const int slot = wgid >> 3;            // 0..31
    const int cb = (slot >> 4) * 8 + xcd;  // 0..15 (col-block pinned to XCD)
    const int ty = slot & 15;
    const int c0 = cb * 64;

    const bool heavy = (ty < 4);
    const u16 *WB1, *WB2 = nullptr;
    const u16* GIsrc;
    const float* bhh;
    int b0 = 0, o0 = 0;
    if (ty < 2)      { b0 = ty * 64;       WB1 = Whsi; WB2 = Whs; GIsrc = GIX; bhh = ws_bhh; }
    else if (ty < 4) { b0 = (ty - 2) * 64; WB1 = Whai; WB2 = Wha; GIsrc = GIA; bhh = wa_bhh; }
    else             { o0 = (ty - 4) * 64; WB1 = Who;             GIsrc = GIO; bhh = wo_bhh; }

    if (tid < 64) {
        if (heavy) {
            int b = b0 + tid;
            int spk = dig[(b * T_ + t) * 2 + 0];
            int adr = dig[(b * T_ + t) * 2 + 1];
            int own = (ty < 2) ? spk : adr;
            int oth = (ty < 2) ? adr : spk;
            roffA1[tid] = (b * R_ + oth) * H_;   // gi-supplement operand rows
            roffA2[tid] = (b * R_ + own) * H_;   // gh operand + output rows
            bIdx[tid] = b;
        } else {
            int mo = o0 + tid;
            int b = mo / 6, j = mo - b * 6;
            int spk = dig[(b * T_ + t) * 2 + 0];
            int adr = dig[(b * T_ + t) * 2 + 1];
            int cnt = 0, role = 0;
            for (int r = 0; r < R_; ++r)
                if (r != spk && r != adr) { if (cnt == j) { role = r; break; } ++cnt; }
            roffA1[tid] = (b * R_ + role) * H_;  // gh operand + output rows
            bIdx[tid] = b;
        }
    }
    __syncthreads();

    const int lane = tid & 63;
    const int wid = tid >> 6;            // 0..7
    const int m0w = (wid >> 2) * 32;     // 0 or 32: wave's M window
    const int w   = wid & 3;             // wave's 16-col state window
    const int fr  = lane & 15;
    const int kq  = (lane >> 4) * 8;

    const int srow = tid >> 3;                                    // 0..63
    const int sce  = (((tid & 7) * 16) ^ ((srow & 7) << 4)) >> 1; // elem col
    const int ldsA = (tid & 448) * 8;                             // wid*512 elems

    f32x4 acc1[3][2] = {};   // WB1 result: gi-suppl (S/A) or gh (O); [g][mt]
    f32x4 acc2[3][2] = {};   // WB2 result: gh (S/A only)

    auto stage = [&](int buf, int k0) {
        async_cp16(Abf_old + roffA1[srow] + k0 + sce, &As1[buf][ldsA]);
        if (heavy)
            async_cp16(Abf_old + roffA2[srow] + k0 + sce, &As2[buf][ldsA]);
#pragma unroll
        for (int p = 0; p < 3; ++p) {    // hat rows p*64 + srow
            int wr = c0 + p * H_ + srow; // W row for gate-part p (r/z/n)
            async_cp16(WB1 + (size_t)wr * H_ + k0 + sce, &Bs1[buf][p * 4096 + ldsA]);
            if (heavy)
                async_cp16(WB2 + (size_t)wr * H_ + k0 + sce, &Bs2[buf][p * 4096 + ldsA]);
        }
    };
    auto compute = [&](int buf) {
#pragma unroll
        for (int kk = 0; kk < 2; ++kk) {
            bf16x8 a1[2], a2[2], b1[3], b2[3];
#pragma unroll
            for (int i = 0; i < 2; ++i) {
                int r = m0w + i * 16 + fr;
                int off = (r * 128 + kk * 64 + kq * 2) ^ ((r & 7) << 4);
                a1[i] = *(const bf16x8*)((const char*)&As1[buf][0] + off);
                if (heavy) a2[i] = *(const bf16x8*)((const char*)&As2[buf][0] + off);
            }
#pragma unroll
            for (int g = 0; g < 3; ++g) {
                int r = g * 64 + w * 16 + fr;
                int off = (r * 128 + kk * 64 + kq * 2) ^ ((r & 7) << 4);
                b1[g] = *(const bf16x8*)((const char*)&Bs1[buf][0] + off);
                if (heavy) b2[g] = *(const bf16x8*)((const char*)&Bs2[buf][0] + off);
            }
#pragma unroll
            for (int g = 0; g < 3; ++g)
#pragma unroll
                for (int i = 0; i < 2; ++i) {
                    acc1[g][i] = __builtin_amdgcn_mfma_f32_16x16x32_bf16(
                        a1[i], b1[g], acc1[g][i], 0, 0, 0);
                    if (heavy)
                        acc2[g][i] = __builtin_amdgcn_mfma_f32_16x16x32_bf16(
                            a2[i], b2[g], acc2[g][i], 0, 0, 0);
                }
        }
    };

    stage(0, 0);
    __syncthreads();
    int cur = 0;
    for (int k0 = 64; k0 < H_; k0 += 64) {
        stage(cur ^ 1, k0);
        compute(cur);
        __syncthreads();
        cur ^= 1;
    }
    compute(cur);

    // ---- gate epilogue: thread holds r,z,n (and gi,gh) for its elements ----
    const int col = c0 + w * 16 + fr;
    const float bh_r = bhh[col];
    const float bh_z = bhh[H_ + col];
    const float bh_n = bhh[2 * H_ + col];
#pragma unroll
    for (int mt = 0; mt < 2; ++mt) {
#pragma unroll
        for (int i = 0; i < 4; ++i) {
            int lr = m0w + mt * 16 + (lane >> 4) * 4 + i;   // local row 0..63
            int b  = bIdx[lr];
            size_t girow = (size_t)(b * Tc + tloc) * H3_;
            float gir = bf2f(GIsrc[girow + col]);
            float giz = bf2f(GIsrc[girow + H_ + col]);
            float gin = bf2f(GIsrc[girow + 2 * H_ + col]);
            float ghr, ghz, ghn;
            if (heavy) {
                gir += acc1[0][mt][i];
                giz += acc1[1][mt][i];
                gin += acc1[2][mt][i];
                ghr = acc2[0][mt][i] + bh_r;
                ghz = acc2[1][mt][i] + bh_z;
                ghn = acc2[2][mt][i] + bh_n;
            } else {
                ghr = acc1[0][mt][i] + bh_r;
                ghz = acc1[1][mt][i] + bh_z;
                ghn = acc1[2][mt][i] + bh_n;
            }
            int ooff = heavy ? roffA2[lr] : roffA1[lr];
            float rg = 1.0f / (1.0f + __expf(-(gir + ghr)));
            float zg = 1.0f / (1.0f + __expf(-(giz + ghz)));
            float ng = tanhf(gin + rg * ghn);
            float h  = Aold[ooff + col];
            float o  = (1.0f - zg) * ng + zg * h;
            Anew[ooff + col] = o;
            Abf_new[ooff + col] = f2bf(o);
        }
    }
}

// ---------------------------------------------------------------------------
extern "C" void kernel_launch(void* const* d_in, const int* in_sizes, int n_in,
                              void* d_out, int out_size, void* d_ws, size_t ws_size,
                              hipStream_t stream) {
    const float* enc    = (const float*)d_in[0];
    const int*   dig    = (const int*)d_in[1];
    const float* ws_ih  = (const float*)d_in[2];
    const float* ws_hh  = (const float*)d_in[3];
    const float* ws_bih = (const float*)d_in[4];
    const float* ws_bhh = (const float*)d_in[5];
    const float* wa_ih  = (const float*)d_in[6];
    const float* wa_hh  = (const float*)d_in[7];
    const float* wa_bih = (const float*)d_in[8];
    const float* wa_bhh = (const float*)d_in[9];
    const float* wo_ih  = (const float*)d_in[10];
    const float* wo_hh  = (const float*)d_in[11];
    const float* wo_bih = (const float*)d_in[12];
    const float* wo_bhh = (const float*)d_in[13];

    float* A0 = (float*)d_out;                    // (B, R, H) final output

    // ---- workspace layout (bytes) ----
    char* p = (char*)d_ws;
    auto take = [&](size_t bytes) { char* q = p; p += (bytes + 255) & ~(size_t)255; return q; };
    u16*   enc_bf = (u16*)  take((size_t)B_ * T_ * E_ * 2);          // 33.6 MB
    u16*   W1     = (u16*)  take((size_t)3 * H3_ * E_ * 2);          // 37.7 MB packed s|a|o
    u16*   W1s    = W1;
    u16*   W1a    = W1 + (size_t)H3_ * E_;
    u16*   W1o    = W1a + (size_t)H3_ * E_;
    u16*   Whsi   = (u16*)  take((size_t)H3_ * H_ * 2);              // 6.3 MB
    u16*   Whai   = (u16*)  take((size_t)H3_ * H_ * 2);
    u16*   Whs    = (u16*)  take((size_t)H3_ * H_ * 2);
    u16*   Wha    = (u16*)  take((size_t)H3_ * H_ * 2);
    u16*   Who    = (u16*)  take((size_t)H3_ * H_ * 2);
    u16*   AbfA   = (u16*)  take((size_t)B_ * R_ * H_ * 2);          // 2 MB
    u16*   AbfB   = (u16*)  take((size_t)B_ * R_ * H_ * 2);          // 2 MB
    float* A1     = (float*)take((size_t)B_ * R_ * H_ * 4);          // 4 MB
    size_t fixed = (size_t)(p - (char*)d_ws);

    // chunk size: largest power-of-two Tc <= 64 fitting GI (3 sets, bf16)
    const size_t per_t = (size_t)3 * B_ * H3_ * 2;                   // 2.36 MB/step
    int Tc = 64;
    while (Tc > 1 && fixed + per_t * (size_t)Tc > ws_size) Tc >>= 1;
    int tcshift = 0;
    while ((1 << tcshift) < Tc) ++tcshift;
    const size_t GI_elems = (size_t)B_ * Tc * H3_;
    u16* GI  = (u16*)take(3 * GI_elems * 2);                         // packed X|A|O
    u16* GIX = GI;
    u16* GIA = GI + GI_elems;
    u16* GIO = GIA + GI_elems;

    dim3 blk(256);
    const size_t A_sz = (size_t)B_ * R_ * H_;

    // zero fp32 state (d_out) and bf16 state copy (read at t=0)
    zero_kernel<<<dim3((int)((A_sz + 255) / 256)), blk, 0, stream>>>(A0, (int)A_sz);
    zero_kernel<<<dim3((int)((A_sz / 2 + 255) / 256)), blk, 0, stream>>>((float*)AbfA, (int)(A_sz / 2));

    // ---- one-time bf16 conversions ----
    {
        int t4;
        t4 = B_ * T_ * E_ / 4;
        conv_bf<<<dim3((t4 + 255) / 256), blk, 0, stream>>>(enc, E_, 0, E_, enc_bf, t4);
        t4 = H3_ * E_ / 4;
        conv_bf<<<dim3((t4 + 255) / 256), blk, 0, stream>>>(ws_ih, E_ + H_, 0, E_, W1s, t4);
        conv_bf<<<dim3((t4 + 255) / 256), blk, 0, stream>>>(wa_ih, E_ + H_, 0, E_, W1a, t4);
        conv_bf<<<dim3((t4 + 255) / 256), blk, 0, stream>>>(wo_ih, E_, 0, E_, W1o, t4);
        t4 = H3_ * H_ / 4;
        conv_bf<<<dim3((t4 + 255) / 256), blk, 0, stream>>>(ws_ih, E_ + H_, E_, H_, Whsi, t4);
        conv_bf<<<dim3((t4 + 255) / 256), blk, 0, stream>>>(wa_ih, E_ + H_, E_, H_, Whai, t4);
        conv_bf<<<dim3((t4 + 255) / 256), blk, 0, stream>>>(ws_hh, H_, 0, H_, Whs, t4);
        conv_bf<<<dim3((t4 + 255) / 256), blk, 0, stream>>>(wa_hh, H_, 0, H_, Wha, t4);
        conv_bf<<<dim3((t4 + 255) / 256), blk, 0, stream>>>(wo_hh, H_, 0, H_, Who, t4);
    }

    float* Aold = A0;
    float* Anew = A1;
    u16* AbfOld = AbfA;
    u16* AbfNew = AbfB;
    for (int t0 = 0; t0 < T_; t0 += Tc) {
        // Phase 1 (chunk): all three input-side GEMMs fused in one dispatch.
        dim3 g1((B_ * Tc) / 128, 72);
        mfma_p1f<<<g1, blk, 0, stream>>>(enc_bf, t0, tcshift, W1,
                                         ws_bih, wa_bih, wo_bih, GI, GI_elems);

        // Phase 2: one fused GEMM+gate dispatch per step.
        for (int t = t0; t < t0 + Tc; ++t) {
            step_fused<<<dim3(256), dim3(512), 0, stream>>>(
                AbfOld, AbfNew, Aold, Anew, dig, t, t - t0, Tc,
                Whsi, Whs, Whai, Wha, Who, GIX, GIA, GIO,
                ws_bhh, wa_bhh, wo_bhh);
            float* tf = Aold; Aold = Anew; Anew = tf;
            u16* tb = AbfOld; AbfOld = AbfNew; AbfNew = tb;
        }
    }
    // T_ = 64 total steps (even): final fp32 state lands in A0 == d_out.
}